// Round 15
// baseline (315.164 us; speedup 1.0000x reference)
//
#include <hip/hip_runtime.h>
#include <hip/hip_bf16.h>
#include <cstdint>

// ============================================================================
// Hybrid e2e STN pipeline, round 14:
//  - GEMM tile 64x64 -> 128x64 with BK=64 kept: 16 MFMA/step/wave vs 8 at the
//    same per-step staging/addr overhead (r13 PMC: VALUBusy 38% vs MfmaUtil
//    16% = VALU-overhead-bound). Row width (128B) and the verified &7 swizzle
//    unchanged; 48KB LDS -> 3 blocks/CU; grids stay >= 384.
//  - 2D XCD partition (MC) retained; everything else identical to r13.
// ============================================================================

#define B_    16
#define HH    512
#define WW    512
#define NF_   1024
#define EMB_  768
#define HEADS_ 12
#define NTOK  256
#define M_    (B_*NTOK)      // 4096
#define KCONV 3072

typedef __bf16 bf16_t;
typedef __bf16 bf16x8 __attribute__((ext_vector_type(8)));
typedef float  f32x4  __attribute__((ext_vector_type(4)));

typedef __attribute__((address_space(1))) const void* gas_t;
typedef __attribute__((address_space(3))) void* las_t;

__device__ __forceinline__ void gload16(const bf16_t* g, bf16_t* l) {
    __builtin_amdgcn_global_load_lds((gas_t)g, (las_t)l, 16, 0, 0);
}

__device__ __forceinline__ float tanh_fast(float x) {
    return 1.0f - 2.0f / (__expf(2.0f * x) + 1.0f);
}

// ---------------------------------------------------------------------------
// rasterize (verified)
// ---------------------------------------------------------------------------
__global__ __launch_bounds__(128)
void raster_kernel(const float* __restrict__ lm, float* __restrict__ seg) {
    int b = blockIdx.x;
    int s = threadIdx.x;
    if (s >= 117) return;
    int seg0 = (s < 43) ? s : ((s < 92) ? s + 1 : s + 2);
    const float* p = lm + (size_t)b * 240;
    int p1x = min(max((int)(p[seg0*2 + 0] * 512.0f), 0), 511);
    int p1y = min(max((int)(p[seg0*2 + 1] * 512.0f), 0), 511);
    int p2x = min(max((int)(p[(seg0+1)*2 + 0] * 512.0f), 0), 511);
    int p2y = min(max((int)(p[(seg0+1)*2 + 1] * 512.0f), 0), 511);
    int dy = p2y - p1y, dx = p2x - p1x;
    int kmax = min(dy, dx);
    float* sb = seg + (size_t)b * (HH*WW);
    for (int k = 0; k < kmax; ++k) {
        int yi = min(p1y + k, 511);
        int xi = min(p1x + k, 511);
        sb[yi*WW + xi] = 1.0f;
    }
}

// ---------------------------------------------------------------------------
// weight prep (verified r12)
// ---------------------------------------------------------------------------
__global__ __launch_bounds__(256)
void prep_weights_kernel(const float* __restrict__ conv_w, bf16_t* __restrict__ conv_wb,
                         const float* __restrict__ stn_w1, float* __restrict__ w1t,
                         const float* __restrict__ pe_w,   bf16_t* __restrict__ pe_wb,
                         const float* __restrict__ qkv_w,  bf16_t* __restrict__ qkv_wb,
                         const float* __restrict__ proj_w, bf16_t* __restrict__ proj_wb,
                         const float* __restrict__ mlp_w1, bf16_t* __restrict__ mlp1_wb,
                         const float* __restrict__ mlp_w2, bf16_t* __restrict__ mlp2_wb) {
    __shared__ float tile[32][33];
    int id = blockIdx.x, tid = threadIdx.x;
    if (id < 1536) {
        int idx = (id*256 + tid) * 8;
        float4 v0 = *reinterpret_cast<const float4*>(conv_w + idx);
        float4 v1 = *reinterpret_cast<const float4*>(conv_w + idx + 4);
        bf16x8 o;
        o[0]=(bf16_t)v0.x; o[1]=(bf16_t)v0.y; o[2]=(bf16_t)v0.z; o[3]=(bf16_t)v0.w;
        o[4]=(bf16_t)v1.x; o[5]=(bf16_t)v1.y; o[6]=(bf16_t)v1.z; o[7]=(bf16_t)v1.w;
        *reinterpret_cast<bf16x8*>(conv_wb + idx) = o;
        return;
    }
    id -= 1536;
    if (id < 200) {
        int idx = id*256 + tid;
        int j = idx >> 10, k = idx & 1023;
        w1t[idx] = stn_w1[k*50 + j];
        return;
    }
    id -= 200;
    const float* in; bf16_t* out; int K, N;
    if      (id < 768)  { in = pe_w;   out = pe_wb;   K = 1024; N = 768;  }
    else if (id < 2496) { in = qkv_w;  out = qkv_wb;  K = 768;  N = 2304; id -= 768;  }
    else if (id < 3072) { in = proj_w; out = proj_wb; K = 768;  N = 768;  id -= 2496; }
    else if (id < 5376) { in = mlp_w1; out = mlp1_wb; K = 768;  N = 3072; id -= 3072; }
    else                { in = mlp_w2; out = mlp2_wb; K = 3072; N = 768;  id -= 5376; }
    int nb = N >> 5;
    int bn = (id % nb) * 32, bk = (id / nb) * 32;
    int r = tid >> 5, c = tid & 31;
    #pragma unroll
    for (int i = 0; i < 4; ++i)
        tile[r + 8*i][c] = in[(size_t)(bk + r + 8*i) * N + bn + c];
    __syncthreads();
    #pragma unroll
    for (int i = 0; i < 4; ++i)
        out[(size_t)(bn + r + 8*i) * K + bk + c] = (bf16_t)tile[c][r + 8*i];
}

// ---------------------------------------------------------------------------
// stn (verified r12)
// ---------------------------------------------------------------------------
__global__ __launch_bounds__(1024)
void stn3_kernel(const float* __restrict__ seg, const float* __restrict__ w1t,
                 const float* __restrict__ b1, const float* __restrict__ w2,
                 const float* __restrict__ b2, float* __restrict__ theta) {
    __shared__ float pl[1024];
    __shared__ float hl[56];
    int b = blockIdx.x, tid = threadIdx.x;
    {
        int ox = tid & 31, oy = tid >> 5;
        const float* sb = seg + (size_t)b*(HH*WW) + (oy*16)*WW + ox*16;
        float s = 0.0f;
        for (int dy = 0; dy < 16; ++dy) {
            #pragma unroll
            for (int dx = 0; dx < 16; ++dx) s += sb[dy*WW + dx];
        }
        pl[tid] = s * (1.0f/256.0f);
    }
    __syncthreads();
    int wave = tid >> 6, lane = tid & 63;
    #pragma unroll
    for (int p = 0; p < 4; ++p) {
        int j = wave + (p << 4);
        if (j < 50) {
            const float* wr = w1t + j*1024;
            float acc = 0.0f;
            #pragma unroll
            for (int i = 0; i < 16; ++i) {
                int k = lane + (i << 6);
                acc = fmaf(pl[k], wr[k], acc);
            }
            #pragma unroll
            for (int off = 32; off; off >>= 1) acc += __shfl_xor(acc, off);
            if (lane == 0) hl[j] = tanhf(acc + b1[j]);
        }
    }
    __syncthreads();
    if (tid < 6) {
        float acc = b2[tid];
        for (int k = 0; k < 50; ++k) acc = fmaf(hl[k], w2[k*6 + tid], acc);
        theta[b*6 + tid] = acc;
    }
}

// ---------------------------------------------------------------------------
// fused affine_grid + grid_sample (verified)
// ---------------------------------------------------------------------------
__global__ __launch_bounds__(256)
void gridsample_kernel(const float* __restrict__ x, const float* __restrict__ seg,
                       const float* __restrict__ theta,
                       float* __restrict__ timg, float* __restrict__ tmask,
                       bf16_t* __restrict__ timgb) {
    size_t idx = (size_t)blockIdx.x * 256 + threadIdx.x;
    int xx = (int)(idx & 511);
    int yy = (int)((idx >> 9) & 511);
    int b  = (int)(idx >> 18);
    __shared__ float th[6];
    if (threadIdx.x < 6) th[threadIdx.x] = theta[b*6 + threadIdx.x];
    __syncthreads();
    float gx = (2.0f*xx + 1.0f) * (1.0f/512.0f) - 1.0f;
    float gy = (2.0f*yy + 1.0f) * (1.0f/512.0f) - 1.0f;
    float g0 = gx*th[0] + gy*th[1] + th[2];
    float g1 = gx*th[3] + gy*th[4] + th[5];
    float fx = ((g0 + 1.0f)*512.0f - 1.0f)*0.5f;
    float fy = ((g1 + 1.0f)*512.0f - 1.0f)*0.5f;
    float x0f = floorf(fx), y0f = floorf(fy);
    float wx1 = fx - x0f,  wy1 = fy - y0f;
    int ix0 = (int)x0f, iy0 = (int)y0f;
    int ix1 = ix0 + 1,  iy1 = iy0 + 1;
    float fy0ok = (iy0 >= 0 && iy0 < HH) ? 1.0f : 0.0f;
    float fy1ok = (iy1 >= 0 && iy1 < HH) ? 1.0f : 0.0f;
    float fx0ok = (ix0 >= 0 && ix0 < WW) ? 1.0f : 0.0f;
    float fx1ok = (ix1 >= 0 && ix1 < WW) ? 1.0f : 0.0f;
    float w00 = (1.0f-wy1)*(1.0f-wx1) * fy0ok * fx0ok;
    float w01 = (1.0f-wy1)*wx1        * fy0ok * fx1ok;
    float w10 = wy1*(1.0f-wx1)        * fy1ok * fx0ok;
    float w11 = wy1*wx1               * fy1ok * fx1ok;
    int cx0 = min(max(ix0,0),511), cx1 = min(max(ix1,0),511);
    int cy0 = min(max(iy0,0),511), cy1 = min(max(iy1,0),511);
    int i00 = cy0*WW + cx0, i01 = cy0*WW + cx1, i10 = cy1*WW + cx0, i11 = cy1*WW + cx1;
    size_t pix = (size_t)yy*WW + xx;
    #pragma unroll
    for (int c = 0; c < 3; ++c) {
        const float* pl = x + ((size_t)(b*3 + c)) * (HH*WW);
        float v = w00*pl[i00] + w01*pl[i01] + w10*pl[i10] + w11*pl[i11];
        timg [((size_t)(b*3 + c))*(HH*WW) + pix] = v;
        timgb[((size_t)(b*3 + c))*(HH*WW) + pix] = (bf16_t)v;
    }
    const float* sp = seg + (size_t)b * (HH*WW);
    float mv = w00*sp[i00] + w01*sp[i01] + w10*sp[i10] + w11*sp[i11];
    tmask[(size_t)b*(HH*WW) + pix] = mv;
}

// ---------------------------------------------------------------------------
// bf16 MFMA GEMM round 14: BM=128, BN=64, BK=64, double-buffered.
// 4 waves as 2m x 2n, each 64x32 = 4x2 frags, 16 MFMA per K-step.
// LDS rows 128B, &7 XOR swizzle (r9-verified; segment bases all %8==0).
// 2D XCD partition (MC x NC=8/MC).
// ---------------------------------------------------------------------------
enum { EPI_CONV=0, EPI_PE=1, EPI_QKV=2, EPI_PROJ=3, EPI_GELU=4, EPI_MLP2=5 };

template<int EPI>
__device__ __forceinline__ void gemm_epilogue128(
        f32x4 (&acc)[4][2], const float* bias, const float* extra,
        bf16_t* Cb, int bm, int bn, int wm, int wn,
        int rr, int g, int N) {
    #pragma unroll
    for (int i = 0; i < 4; ++i) {
        #pragma unroll
        for (int j = 0; j < 2; ++j) {
            #pragma unroll
            for (int r = 0; r < 4; ++r) {
                int m = bm + wm + i*16 + g*4 + r;
                int n = bn + wn + j*16 + rr;
                size_t o = (size_t)m * N + n;
                float v = acc[i][j][r] + bias[n];
                if (EPI == EPI_CONV) {
                    Cb[o] = (bf16_t)fmaxf(v, 0.0f);
                } else if (EPI == EPI_PE) {
                    Cb[o] = (bf16_t)(v + extra[(size_t)(m & 255)*N + n]);
                } else if (EPI == EPI_QKV) {
                    Cb[o] = (bf16_t)v;
                } else if (EPI == EPI_PROJ || EPI == EPI_MLP2) {
                    Cb[o] = (bf16_t)(v + (float)Cb[o]);
                } else if (EPI == EPI_GELU) {
                    float u = v;
                    float gl = 0.5f*u*(1.0f + tanh_fast(0.7978845608028654f*(u + 0.044715f*u*u*u)));
                    Cb[o] = (bf16_t)gl;
                }
            }
        }
    }
}

template<int EPI, int MC>
__global__ __launch_bounds__(256)
void gemm128_kernel(const bf16_t* __restrict__ A, const bf16_t* __restrict__ Bt,
                    const float* __restrict__ bias, const float* __restrict__ extra,
                    bf16_t* __restrict__ Cb,
                    int M, int N, int K) {
    constexpr int NC = 8 / MC;
    __shared__ __align__(16) bf16_t As[2][128*64];   // 32 KB
    __shared__ __align__(16) bf16_t Bs[2][64*64];    // 16 KB
    const int tid = threadIdx.x;
    const int nM = M >> 7, nN = N >> 6;
    const int SM = nM / MC, SN = nN / NC;
    const int xcd = blockIdx.x & 7;
    const int wdx = blockIdx.x >> 3;
    const int mc  = xcd / NC, nc = xcd % NC;
    const int bm = (mc*SM + wdx / SN) * 128;
    const int bn = (nc*SN + wdx % SN) * 64;
    const int lane = tid & 63, w = tid >> 6;
    const int rr = lane & 15, g = lane >> 4;
    const int wm = (w & 1) * 64, wn = (w >> 1) * 32;
    const int sr = tid >> 3;                        // 0..31 per segment
    const int sc = ((tid & 7) ^ (sr & 7)) * 8;      // swizzled source col
    const bf16_t* gA0 = A  + (size_t)(bm + sr)      * K + sc;
    const bf16_t* gA1 = A  + (size_t)(bm + 32 + sr) * K + sc;
    const bf16_t* gA2 = A  + (size_t)(bm + 64 + sr) * K + sc;
    const bf16_t* gA3 = A  + (size_t)(bm + 96 + sr) * K + sc;
    const bf16_t* gB0 = Bt + (size_t)(bn + sr)      * K + sc;
    const bf16_t* gB1 = Bt + (size_t)(bn + 32 + sr) * K + sc;

    auto STAGE = [&](int buf, int k0) {
        gload16(gA0 + k0, As[buf] + w*512);
        gload16(gA1 + k0, As[buf] + 2048 + w*512);
        gload16(gA2 + k0, As[buf] + 4096 + w*512);
        gload16(gA3 + k0, As[buf] + 6144 + w*512);
        gload16(gB0 + k0, Bs[buf] + w*512);
        gload16(gB1 + k0, Bs[buf] + 2048 + w*512);
    };

    const int s0 = (0*4 + g) ^ (rr & 7);
    const int s1 = (1*4 + g) ^ (rr & 7);

    f32x4 acc[4][2] = {};
    STAGE(0, 0);
    __syncthreads();
    int cur = 0;
    for (int k0 = 0; k0 < K; k0 += 64) {
        if (k0 + 64 < K) STAGE(cur ^ 1, k0 + 64);
        bf16x8 af[4][2], bfv[2][2];
        #pragma unroll
        for (int i = 0; i < 4; ++i) {
            int ra = (wm + i*16 + rr) * 64;
            af[i][0] = *reinterpret_cast<const bf16x8*>(As[cur] + ra + s0*8);
            af[i][1] = *reinterpret_cast<const bf16x8*>(As[cur] + ra + s1*8);
        }
        #pragma unroll
        for (int j = 0; j < 2; ++j) {
            int rb = (wn + j*16 + rr) * 64;
            bfv[j][0] = *reinterpret_cast<const bf16x8*>(Bs[cur] + rb + s0*8);
            bfv[j][1] = *reinterpret_cast<const bf16x8*>(Bs[cur] + rb + s1*8);
        }
        #pragma unroll
        for (int ks = 0; ks < 2; ++ks)
            #pragma unroll
            for (int i = 0; i < 4; ++i)
                #pragma unroll
                for (int j = 0; j < 2; ++j)
                    acc[i][j] = __builtin_amdgcn_mfma_f32_16x16x32_bf16(
                        af[i][ks], bfv[j][ks], acc[i][j], 0, 0, 0);
        __syncthreads();
        cur ^= 1;
    }
    gemm_epilogue128<EPI>(acc, bias, extra, Cb, bm, bn, wm, wn, rr, g, N);
}

// conv GEMM: implicit im2col, BM=128/BN=64/BK=64. M=4096, N=1024, K=3072.
__global__ __launch_bounds__(256)
void gemm_conv128_kernel(const bf16_t* __restrict__ timgb, const bf16_t* __restrict__ Bt,
                         const float* __restrict__ bias, bf16_t* __restrict__ Cb) {
    const int N = NF_, K = KCONV;
    __shared__ __align__(16) bf16_t As[2][128*64];
    __shared__ __align__(16) bf16_t Bs[2][64*64];
    const int tid = threadIdx.x;
    const int nN   = N >> 6;                 // 16
    const int nblk = (M_ >> 7) * nN;         // 512
    const int q    = nblk >> 3;
    const int id   = (blockIdx.x & 7) * q + (blockIdx.x >> 3);
    const int bm = (id / nN) * 128, bn = (id % nN) * 64;
    const int lane = tid & 63, w = tid >> 6;
    const int rr = lane & 15, g = lane >> 4;
    const int wm = (w & 1) * 64, wn = (w >> 1) * 32;
    const int sr = tid >> 3;
    const int s  = (tid & 7) ^ (sr & 7);
    // rows bm+seg*32+sr, seg=0..3 -> image offsets
    size_t aoff[4];
    #pragma unroll
    for (int seg = 0; seg < 4; ++seg) {
        int row = bm + seg*32 + sr;
        int b0 = row >> 8, py = (row >> 4) & 15, px = row & 15;
        aoff[seg] = (size_t)b0*786432 + py*16384 + px*32 + (s>>2)*512 + (s&3)*8;
    }
    const bf16_t* gB0 = Bt + (size_t)(bn + sr)      * K + s*8;
    const bf16_t* gB1 = Bt + (size_t)(bn + 32 + sr) * K + s*8;

    auto STAGE = [&](int buf, int k0) {
        int c   = k0 >> 10;
        int ky0 = (k0 >> 5) & 31;
        size_t koff = (size_t)c*262144 + (size_t)ky0*512;
        gload16(timgb + aoff[0] + koff, As[buf] + w*512);
        gload16(timgb + aoff[1] + koff, As[buf] + 2048 + w*512);
        gload16(timgb + aoff[2] + koff, As[buf] + 4096 + w*512);
        gload16(timgb + aoff[3] + koff, As[buf] + 6144 + w*512);
        gload16(gB0 + k0, Bs[buf] + w*512);
        gload16(gB1 + k0, Bs[buf] + 2048 + w*512);
    };

    const int s0 = (0*4 + g) ^ (rr & 7);
    const int s1 = (1*4 + g) ^ (rr & 7);

    f32x4 acc[4][2] = {};
    STAGE(0, 0);
    __syncthreads();
    int cur = 0;
    for (int k0 = 0; k0 < K; k0 += 64) {
        if (k0 + 64 < K) STAGE(cur ^ 1, k0 + 64);
        bf16x8 af[4][2], bfv[2][2];
        #pragma unroll
        for (int i = 0; i < 4; ++i) {
            int ra = (wm + i*16 + rr) * 64;
            af[i][0] = *reinterpret_cast<const bf16x8*>(As[cur] + ra + s0*8);
            af[i][1] = *reinterpret_cast<const bf16x8*>(As[cur] + ra + s1*8);
        }
        #pragma unroll
        for (int j = 0; j < 2; ++j) {
            int rb = (wn + j*16 + rr) * 64;
            bfv[j][0] = *reinterpret_cast<const bf16x8*>(Bs[cur] + rb + s0*8);
            bfv[j][1] = *reinterpret_cast<const bf16x8*>(Bs[cur] + rb + s1*8);
        }
        #pragma unroll
        for (int ks = 0; ks < 2; ++ks)
            #pragma unroll
            for (int i = 0; i < 4; ++i)
                #pragma unroll
                for (int j = 0; j < 2; ++j)
                    acc[i][j] = __builtin_amdgcn_mfma_f32_16x16x32_bf16(
                        af[i][ks], bfv[j][ks], acc[i][j], 0, 0, 0);
        __syncthreads();
        cur ^= 1;
    }
    gemm_epilogue128<EPI_CONV>(acc, bias, nullptr, Cb, bm, bn, wm, wn, rr, g, N);
}

// ---------------------------------------------------------------------------
// layernorm (verified r12)
// ---------------------------------------------------------------------------
__global__ __launch_bounds__(256)
void ln_kernel(const bf16_t* __restrict__ x, const float* __restrict__ g,
               const float* __restrict__ be, bf16_t* __restrict__ out) {
    int r = blockIdx.x, tid = threadIdx.x;
    const bf16_t* xr = x + (size_t)r * EMB_;
    float v0 = (float)xr[tid], v1 = (float)xr[tid+256], v2 = (float)xr[tid+512];
    float s = v0+v1+v2, s2 = v0*v0 + v1*v1 + v2*v2;
    __shared__ float red[8];
    #pragma unroll
    for (int off = 32; off; off >>= 1) { s += __shfl_xor(s, off); s2 += __shfl_xor(s2, off); }
    if ((tid & 63) == 0) { red[tid>>6] = s; red[4 + (tid>>6)] = s2; }
    __syncthreads();
    s  = red[0]+red[1]+red[2]+red[3];
    s2 = red[4]+red[5]+red[6]+red[7];
    float mean = s * (1.0f/768.0f);
    float var  = s2 * (1.0f/768.0f) - mean*mean;
    float rstd = rsqrtf(var + 1e-5f);
    bf16_t* orow = out + (size_t)r * EMB_;
    orow[tid]     = (bf16_t)((v0-mean)*rstd*g[tid]     + be[tid]);
    orow[tid+256] = (bf16_t)((v1-mean)*rstd*g[tid+256] + be[tid+256]);
    orow[tid+512] = (bf16_t)((v2-mean)*rstd*g[tid+512] + be[tid+512]);
}

// ---------------------------------------------------------------------------
// attention: MFMA flash-chunked (verified r5-r13)
// ---------------------------------------------------------------------------
__global__ __launch_bounds__(256)
void attn_kernel5(const bf16_t* __restrict__ qkv, bf16_t* __restrict__ o) {
    __shared__ __align__(16) bf16_t Ks[256*72];
    __shared__ __align__(16) bf16_t Vt[64*264];
    __shared__ __align__(16) bf16_t Ps[4][64*72];
    const int tid  = threadIdx.x;
    const int lane = tid & 63, w = tid >> 6;
    const int rr   = lane & 15, g = lane >> 4;
    const int h = blockIdx.x % HEADS_;
    const int b = blockIdx.x / HEADS_;
    const bf16_t* base = qkv + (size_t)(b*256)*2304;

    {
        const bf16_t* kr = base + (size_t)tid*2304 + 768  + h*64;
        const bf16_t* vr = base + (size_t)tid*2304 + 1536 + h*64;
        bf16_t* kd = Ks + tid*72;
        #pragma unroll
        for (int c2 = 0; c2 < 8; ++c2) {
            *reinterpret_cast<bf16x8*>(kd + c2*8) =
                *reinterpret_cast<const bf16x8*>(kr + c2*8);
            bf16x8 v = *reinterpret_cast<const bf16x8*>(vr + c2*8);
            #pragma unroll
            for (int e = 0; e < 8; ++e)
                Vt[(c2*8 + e)*264 + tid] = v[e];
        }
    }

    bf16x8 qf[4][2];
    #pragma unroll
    for (int i = 0; i < 4; ++i)
        #pragma unroll
        for (int ks = 0; ks < 2; ++ks)
            qf[i][ks] = *reinterpret_cast<const bf16x8*>(
                base + (size_t)(w*64 + i*16 + rr)*2304 + h*64 + ks*32 + g*8);

    f32x4 oacc[4][4] = {};
    float lacc[4][4] = {};
    __syncthreads();

    bf16_t* Pw = Ps[w];
    for (int kc = 0; kc < 4; ++kc) {
        f32x4 sacc[4][4] = {};
        #pragma unroll
        for (int ks = 0; ks < 2; ++ks) {
            bf16x8 kf[4];
            #pragma unroll
            for (int j = 0; j < 4; ++j)
                kf[j] = *reinterpret_cast<const bf16x8*>(
                    Ks + (size_t)(kc*64 + j*16 + rr)*72 + ks*32 + g*8);
            #pragma unroll
            for (int i = 0; i < 4; ++i)
                #pragma unroll
                for (int j = 0; j < 4; ++j)
                    sacc[i][j] = __builtin_amdgcn_mfma_f32_16x16x32_bf16(
                        qf[i][ks], kf[j], sacc[i][j], 0, 0, 0);
        }
        #pragma unroll
        for (int i = 0; i < 4; ++i) {
            #pragma unroll
            for (int r = 0; r < 4; ++r) {
                int prow = i*16 + g*4 + r;
                float ps = 0.0f;
                #pragma unroll
                for (int j = 0; j < 4; ++j) {
                    float p = __expf(sacc[i][j][r] * 0.125f);
                    ps += p;
                    Pw[prow*72 + j*16 + rr] = (bf16_t)p;
                }
                lacc[i][r] += ps;
            }
        }
        #pragma unroll
        for (int ks = 0; ks < 2; ++ks) {
            bf16x8 pa[4], vb[4];
            #pragma unroll
            for (int i = 0; i < 4; ++i)
                pa[i] = *reinterpret_cast<const bf16x8*>(
                    Pw + (size_t)(i*16 + rr)*72 + ks*32 + g*8);
            #pragma unroll
            for (int n = 0; n < 4; ++n)
                vb[n] = *reinterpret_cast<const bf16x8*>(
                    Vt + (size_t)(n*16 + rr)*264 + kc*64 + ks*32 + g*8);
            #pragma unroll
            for (int i = 0; i < 4; ++i)
                #pragma unroll
                for (int n = 0; n < 4; ++n)
                    oacc[i][n] = __builtin_amdgcn_mfma_f32_16x16x32_bf16(
                        pa[i], vb[n], oacc[i][n], 0, 0, 0);
        }
    }

    #pragma unroll
    for (int i = 0; i < 4; ++i) {
        #pragma unroll
        for (int r = 0; r < 4; ++r) {
            float v = lacc[i][r];
            v += __shfl_xor(v, 1);
            v += __shfl_xor(v, 2);
            v += __shfl_xor(v, 4);
            v += __shfl_xor(v, 8);
            lacc[i][r] = 1.0f / v;
        }
    }
    #pragma unroll
    for (int i = 0; i < 4; ++i) {
        #pragma unroll
        for (int r = 0; r < 4; ++r) {
            int qrow = w*64 + i*16 + g*4 + r;
            bf16_t* orow = o + (size_t)(b*256 + qrow)*EMB_ + h*64;
            float inv = lacc[i][r];
            #pragma unroll
            for (int n = 0; n < 4; ++n)
                orow[n*16 + rr] = (bf16_t)(oacc[i][n][r] * inv);
        }
    }
}

// ---------------------------------------------------------------------------
// head (verified r12)
// ---------------------------------------------------------------------------
__global__ __launch_bounds__(768)
void head_kernel2(const bf16_t* __restrict__ tok, const float* __restrict__ fcw,
                  const float* __restrict__ fcb, float* __restrict__ scores) {
    const int bx[6][4] = {{0,6,0,8},{4,11,0,8},{9,16,0,8},{0,6,8,16},{4,11,8,16},{9,16,8,16}};
    int box = blockIdx.x % 6, b = blockIdx.x / 6;
    int r0 = bx[box][0], r1 = bx[box][1], c0 = bx[box][2], c1 = bx[box][3];
    int rh = r1 - r0, rw = c1 - c0;
    __shared__ float wl[256];
    __shared__ float red[48];
    int tid = threadIdx.x;
    if (tid < 256) {
        int py = tid >> 4, px = tid & 15;
        float w = 0.0f;
        if (py >= r0 && py < r1 && px >= c0 && px < c1) {
            int ly = py - r0, lx = px - c0;
            float cy = 0.0f, cx = 0.0f;
            for (int o = 0; o < 16; ++o) {
                float sy = (o + 0.5f) * (float)rh * (1.0f/16.0f) - 0.5f;
                sy = fminf(fmaxf(sy, 0.0f), (float)(rh - 1));
                int i0 = (int)floorf(sy); float t = sy - (float)i0;
                if (ly == i0)     cy += 1.0f - t;
                if (ly == i0 + 1) cy += t;
                float sx = (o + 0.5f) * (float)rw * (1.0f/16.0f) - 0.5f;
                sx = fminf(fmaxf(sx, 0.0f), (float)(rw - 1));
                int j0 = (int)floorf(sx); float u = sx - (float)j0;
                if (lx == j0)     cx += 1.0f - u;
                if (lx == j0 + 1) cx += u;
            }
            w = (cy * (1.0f/16.0f)) * (cx * (1.0f/16.0f));
        }
        wl[tid] = w;
    }
    __syncthreads();
    float f = 0.0f;
    for (int iy = r0; iy < r1; ++iy)
        for (int ix = c0; ix < c1; ++ix) {
            int p = iy*16 + ix;
            f = fmaf(wl[p], (float)tok[((size_t)(b*256 + p))*EMB_ + tid], f);
        }
    float p0 = f * fcw[tid*4+0];
    float p1 = f * fcw[tid*4+1];
    float p2 = f * fcw[tid*4+2];
    float p3 = f * fcw[tid*4+3];
    #pragma unroll
    for (int off = 32; off; off >>= 1) {
        p0 += __shfl_xor(p0, off); p1 += __shfl_xor(p1, off);
        p2 += __shfl_xor(p2, off); p3 += __shfl_xor(p3, off);
    }
    int wv = tid >> 6;
    if ((tid & 63) == 0) {
        red[wv*4+0] = p0; red[wv*4+1] = p1; red[wv*4+2] = p2; red[wv*4+3] = p3;
    }
    __syncthreads();
    if (tid == 0) {
        float lg[4];
        #pragma unroll
        for (int cc = 0; cc < 4; ++cc) {
            float s = fcb[cc];
            for (int v = 0; v < 12; ++v) s += red[v*4+cc];
            lg[cc] = s;
        }
        float mx = fmaxf(fmaxf(lg[0],lg[1]), fmaxf(lg[2],lg[3]));
        float e0 = expf(lg[0]-mx), e1 = expf(lg[1]-mx), e2 = expf(lg[2]-mx), e3 = expf(lg[3]-mx);
        float inv = 1.0f/(e0+e1+e2+e3);
        float* out = scores + (size_t)(b*6 + box)*4;
        out[0] = e0*inv; out[1] = e1*inv; out[2] = e2*inv; out[3] = e3*inv;
    }
}

// ===========================================================================
extern "C" void kernel_launch(void* const* d_in, const int* in_sizes, int n_in,
                              void* d_out, int out_size, void* d_ws, size_t ws_size,
                              hipStream_t stream) {
    (void)in_sizes; (void)n_in; (void)out_size; (void)ws_size;
    const float* x       = (const float*)d_in[0];
    const float* lm      = (const float*)d_in[1];
    const float* stn_w1  = (const float*)d_in[2];
    const float* stn_b1  = (const float*)d_in[3];
    const float* stn_w2  = (const float*)d_in[4];
    const float* stn_b2  = (const float*)d_in[5];
    const float* conv_w  = (const float*)d_in[6];
    const float* conv_b  = (const float*)d_in[7];
    const float* pe_w    = (const float*)d_in[8];
    const float* pe_b    = (const float*)d_in[9];
    const float* pos     = (const float*)d_in[10];
    const float* ln1_g   = (const float*)d_in[11];
    const float* ln1_b   = (const float*)d_in[12];
    const float* qkv_w   = (const float*)d_in[13];
    const float* qkv_b   = (const float*)d_in[14];
    const float* proj_w  = (const float*)d_in[15];
    const float* proj_b  = (const float*)d_in[16];
    const float* ln2_g   = (const float*)d_in[17];
    const float* ln2_b   = (const float*)d_in[18];
    const float* mlp_w1  = (const float*)d_in[19];
    const float* mlp_b1  = (const float*)d_in[20];
    const float* mlp_w2  = (const float*)d_in[21];
    const float* mlp_b2  = (const float*)d_in[22];
    const float* fc_w    = (const float*)d_in[23];
    const float* fc_b    = (const float*)d_in[24];

    float* out    = (float*)d_out;
    float* scores = out;
    float* timg   = out + 384;
    float* tmask  = out + 384 + (size_t)B_*3*HH*WW;

    char* ws = (char*)d_ws;
    size_t off = 0;
    auto alloc = [&](size_t bytes) {
        off = (off + 255) & ~(size_t)255;
        void* p = ws + off; off += bytes; return p;
    };
    char*   slotBig = (char*)alloc(25165824);            // seg -> hidden
    char*   slotT   = (char*)alloc((size_t)B_*3*HH*WW*2); // timgb -> qkvb
    char*   slotC   = (char*)alloc((size_t)M_*NF_*2);     // featC -> obuf
    bf16_t* tok     = (bf16_t*)alloc((size_t)M_*EMB_*2);
    bf16_t* tbuf    = (bf16_t*)alloc((size_t)M_*EMB_*2);
    bf16_t* conv_wb = (bf16_t*)alloc((size_t)NF_*KCONV*2);
    bf16_t* pe_wb   = (bf16_t*)alloc((size_t)EMB_*NF_*2);
    bf16_t* qkv_wb  = (bf16_t*)alloc((size_t)3*EMB_*EMB_*2);
    bf16_t* proj_wb = (bf16_t*)alloc((size_t)EMB_*EMB_*2);
    bf16_t* mlp1_wb = (bf16_t*)alloc((size_t)4*EMB_*EMB_*2);
    bf16_t* mlp2_wb = (bf16_t*)alloc((size_t)EMB_*4*EMB_*2);
    float*  w1t     = (float*)alloc(50*1024*4);
    float*  theta   = (float*)alloc(96*4);

    float*  seg    = (float*)slotBig;
    bf16_t* hidden = (bf16_t*)slotBig;
    bf16_t* timgb  = (bf16_t*)slotT;
    bf16_t* qkvb   = (bf16_t*)slotT;
    bf16_t* featC  = (bf16_t*)slotC;
    bf16_t* obuf   = (bf16_t*)slotC;

    // weight prep (fused)
    prep_weights_kernel<<<9416, 256, 0, stream>>>(
        conv_w, conv_wb, stn_w1, w1t, pe_w, pe_wb, qkv_w, qkv_wb,
        proj_w, proj_wb, mlp_w1, mlp1_wb, mlp_w2, mlp2_wb);

    // mask path
    hipMemsetAsync(seg, 0, (size_t)B_*HH*WW*sizeof(float), stream);
    raster_kernel<<<B_, 128, 0, stream>>>(lm, seg);
    stn3_kernel<<<B_, 1024, 0, stream>>>(seg, w1t, stn_b1, stn_w2, stn_b2, theta);
    gridsample_kernel<<<(B_*HH*WW)/256, 256, 0, stream>>>(x, seg, theta, timg, tmask, timgb);

    // conv as implicit-im2col GEMM (128x64 tiles, 512 blocks)
    gemm_conv128_kernel<<<(M_/128)*(NF_/64), 256, 0, stream>>>(
        timgb, conv_wb, conv_b, featC);

    // patch embed + pos -> tok   [384 blocks, MC=8]
    gemm128_kernel<EPI_PE, 8><<<(M_/128)*(EMB_/64), 256, 0, stream>>>(
        featC, pe_wb, pe_b, pos, tok, M_, EMB_, NF_);

    // LN1 -> qkv   [1152 blocks, MC=4: 3.3MB/XCD fits L2]
    ln_kernel<<<M_, 256, 0, stream>>>(tok, ln1_g, ln1_b, tbuf);
    gemm128_kernel<EPI_QKV, 4><<<(M_/128)*(3*EMB_/64), 256, 0, stream>>>(
        tbuf, qkv_wb, qkv_b, nullptr, qkvb, M_, 3*EMB_, EMB_);

    // attention (MFMA)
    attn_kernel5<<<B_*HEADS_, 256, 0, stream>>>(qkvb, obuf);

    // proj + residual   [384 blocks, MC=8]
    gemm128_kernel<EPI_PROJ, 8><<<(M_/128)*(EMB_/64), 256, 0, stream>>>(
        obuf, proj_wb, proj_b, nullptr, tok, M_, EMB_, EMB_);

    // LN2 -> mlp   [mlp1 1536 blocks MC=4; mlp2 384 blocks MC=8]
    ln_kernel<<<M_, 256, 0, stream>>>(tok, ln2_g, ln2_b, tbuf);
    gemm128_kernel<EPI_GELU, 4><<<(M_/128)*(4*EMB_/64), 256, 0, stream>>>(
        tbuf, mlp1_wb, mlp_b1, nullptr, hidden, M_, 4*EMB_, EMB_);
    gemm128_kernel<EPI_MLP2, 8><<<(M_/128)*(EMB_/64), 256, 0, stream>>>(
        hidden, mlp2_wb, mlp_b2, nullptr, tok, M_, EMB_, 4*EMB_);

    // head
    head_kernel2<<<B_*6, 768, 0, stream>>>(tok, fc_w, fc_b, scores);
}

// Round 17
// 296.842 us; speedup vs baseline: 1.0617x; 1.0617x over previous
//
#include <hip/hip_runtime.h>
#include <hip/hip_bf16.h>
#include <cstdint>

// ============================================================================
// Hybrid e2e STN pipeline, round 16 = round-13 verified optimum (297.9us,
// passed full timing validation r12/r13; r15 failure unreproducible from code
// analysis -> transient).
//  - GEMMs: 64x64 tile, BK=64, 4 waves of 32x32, row&7 XOR swizzle,
//    2D XCD partition (MC x NC) so wide-N working sets fit per-XCD L2.
//  - bf16 residual stream, fused weight-prep / stn / head.
//  - attention: MFMA flash-chunked.
// ============================================================================

#define B_    16
#define HH    512
#define WW    512
#define NF_   1024
#define EMB_  768
#define HEADS_ 12
#define NTOK  256
#define M_    (B_*NTOK)      // 4096
#define KCONV 3072

typedef __bf16 bf16_t;
typedef __bf16 bf16x8 __attribute__((ext_vector_type(8)));
typedef float  f32x4  __attribute__((ext_vector_type(4)));

typedef __attribute__((address_space(1))) const void* gas_t;
typedef __attribute__((address_space(3))) void* las_t;

__device__ __forceinline__ void gload16(const bf16_t* g, bf16_t* l) {
    __builtin_amdgcn_global_load_lds((gas_t)g, (las_t)l, 16, 0, 0);
}

__device__ __forceinline__ float tanh_fast(float x) {
    return 1.0f - 2.0f / (__expf(2.0f * x) + 1.0f);
}

// ---------------------------------------------------------------------------
// rasterize (verified)
// ---------------------------------------------------------------------------
__global__ __launch_bounds__(128)
void raster_kernel(const float* __restrict__ lm, float* __restrict__ seg) {
    int b = blockIdx.x;
    int s = threadIdx.x;
    if (s >= 117) return;
    int seg0 = (s < 43) ? s : ((s < 92) ? s + 1 : s + 2);
    const float* p = lm + (size_t)b * 240;
    int p1x = min(max((int)(p[seg0*2 + 0] * 512.0f), 0), 511);
    int p1y = min(max((int)(p[seg0*2 + 1] * 512.0f), 0), 511);
    int p2x = min(max((int)(p[(seg0+1)*2 + 0] * 512.0f), 0), 511);
    int p2y = min(max((int)(p[(seg0+1)*2 + 1] * 512.0f), 0), 511);
    int dy = p2y - p1y, dx = p2x - p1x;
    int kmax = min(dy, dx);
    float* sb = seg + (size_t)b * (HH*WW);
    for (int k = 0; k < kmax; ++k) {
        int yi = min(p1y + k, 511);
        int xi = min(p1x + k, 511);
        sb[yi*WW + xi] = 1.0f;
    }
}

// ---------------------------------------------------------------------------
// weight prep (verified r12): conv convert + w1 transpose + 5 transposes
// ---------------------------------------------------------------------------
__global__ __launch_bounds__(256)
void prep_weights_kernel(const float* __restrict__ conv_w, bf16_t* __restrict__ conv_wb,
                         const float* __restrict__ stn_w1, float* __restrict__ w1t,
                         const float* __restrict__ pe_w,   bf16_t* __restrict__ pe_wb,
                         const float* __restrict__ qkv_w,  bf16_t* __restrict__ qkv_wb,
                         const float* __restrict__ proj_w, bf16_t* __restrict__ proj_wb,
                         const float* __restrict__ mlp_w1, bf16_t* __restrict__ mlp1_wb,
                         const float* __restrict__ mlp_w2, bf16_t* __restrict__ mlp2_wb) {
    __shared__ float tile[32][33];
    int id = blockIdx.x, tid = threadIdx.x;
    if (id < 1536) {
        int idx = (id*256 + tid) * 8;
        float4 v0 = *reinterpret_cast<const float4*>(conv_w + idx);
        float4 v1 = *reinterpret_cast<const float4*>(conv_w + idx + 4);
        bf16x8 o;
        o[0]=(bf16_t)v0.x; o[1]=(bf16_t)v0.y; o[2]=(bf16_t)v0.z; o[3]=(bf16_t)v0.w;
        o[4]=(bf16_t)v1.x; o[5]=(bf16_t)v1.y; o[6]=(bf16_t)v1.z; o[7]=(bf16_t)v1.w;
        *reinterpret_cast<bf16x8*>(conv_wb + idx) = o;
        return;
    }
    id -= 1536;
    if (id < 200) {
        int idx = id*256 + tid;
        int j = idx >> 10, k = idx & 1023;
        w1t[idx] = stn_w1[k*50 + j];
        return;
    }
    id -= 200;
    const float* in; bf16_t* out; int K, N;
    if      (id < 768)  { in = pe_w;   out = pe_wb;   K = 1024; N = 768;  }
    else if (id < 2496) { in = qkv_w;  out = qkv_wb;  K = 768;  N = 2304; id -= 768;  }
    else if (id < 3072) { in = proj_w; out = proj_wb; K = 768;  N = 768;  id -= 2496; }
    else if (id < 5376) { in = mlp_w1; out = mlp1_wb; K = 768;  N = 3072; id -= 3072; }
    else                { in = mlp_w2; out = mlp2_wb; K = 3072; N = 768;  id -= 5376; }
    int nb = N >> 5;
    int bn = (id % nb) * 32, bk = (id / nb) * 32;
    int r = tid >> 5, c = tid & 31;
    #pragma unroll
    for (int i = 0; i < 4; ++i)
        tile[r + 8*i][c] = in[(size_t)(bk + r + 8*i) * N + bn + c];
    __syncthreads();
    #pragma unroll
    for (int i = 0; i < 4; ++i)
        out[(size_t)(bn + r + 8*i) * K + bk + c] = (bf16_t)tile[c][r + 8*i];
}

// ---------------------------------------------------------------------------
// stn (verified r12): pooling fused, 16 blocks x 1024 threads
// ---------------------------------------------------------------------------
__global__ __launch_bounds__(1024)
void stn3_kernel(const float* __restrict__ seg, const float* __restrict__ w1t,
                 const float* __restrict__ b1, const float* __restrict__ w2,
                 const float* __restrict__ b2, float* __restrict__ theta) {
    __shared__ float pl[1024];
    __shared__ float hl[56];
    int b = blockIdx.x, tid = threadIdx.x;
    {
        int ox = tid & 31, oy = tid >> 5;
        const float* sb = seg + (size_t)b*(HH*WW) + (oy*16)*WW + ox*16;
        float s = 0.0f;
        for (int dy = 0; dy < 16; ++dy) {
            #pragma unroll
            for (int dx = 0; dx < 16; ++dx) s += sb[dy*WW + dx];
        }
        pl[tid] = s * (1.0f/256.0f);
    }
    __syncthreads();
    int wave = tid >> 6, lane = tid & 63;
    #pragma unroll
    for (int p = 0; p < 4; ++p) {
        int j = wave + (p << 4);
        if (j < 50) {
            const float* wr = w1t + j*1024;
            float acc = 0.0f;
            #pragma unroll
            for (int i = 0; i < 16; ++i) {
                int k = lane + (i << 6);
                acc = fmaf(pl[k], wr[k], acc);
            }
            #pragma unroll
            for (int off = 32; off; off >>= 1) acc += __shfl_xor(acc, off);
            if (lane == 0) hl[j] = tanhf(acc + b1[j]);
        }
    }
    __syncthreads();
    if (tid < 6) {
        float acc = b2[tid];
        for (int k = 0; k < 50; ++k) acc = fmaf(hl[k], w2[k*6 + tid], acc);
        theta[b*6 + tid] = acc;
    }
}

// ---------------------------------------------------------------------------
// fused affine_grid + grid_sample (verified)
// ---------------------------------------------------------------------------
__global__ __launch_bounds__(256)
void gridsample_kernel(const float* __restrict__ x, const float* __restrict__ seg,
                       const float* __restrict__ theta,
                       float* __restrict__ timg, float* __restrict__ tmask,
                       bf16_t* __restrict__ timgb) {
    size_t idx = (size_t)blockIdx.x * 256 + threadIdx.x;
    int xx = (int)(idx & 511);
    int yy = (int)((idx >> 9) & 511);
    int b  = (int)(idx >> 18);
    __shared__ float th[6];
    if (threadIdx.x < 6) th[threadIdx.x] = theta[b*6 + threadIdx.x];
    __syncthreads();
    float gx = (2.0f*xx + 1.0f) * (1.0f/512.0f) - 1.0f;
    float gy = (2.0f*yy + 1.0f) * (1.0f/512.0f) - 1.0f;
    float g0 = gx*th[0] + gy*th[1] + th[2];
    float g1 = gx*th[3] + gy*th[4] + th[5];
    float fx = ((g0 + 1.0f)*512.0f - 1.0f)*0.5f;
    float fy = ((g1 + 1.0f)*512.0f - 1.0f)*0.5f;
    float x0f = floorf(fx), y0f = floorf(fy);
    float wx1 = fx - x0f,  wy1 = fy - y0f;
    int ix0 = (int)x0f, iy0 = (int)y0f;
    int ix1 = ix0 + 1,  iy1 = iy0 + 1;
    float fy0ok = (iy0 >= 0 && iy0 < HH) ? 1.0f : 0.0f;
    float fy1ok = (iy1 >= 0 && iy1 < HH) ? 1.0f : 0.0f;
    float fx0ok = (ix0 >= 0 && ix0 < WW) ? 1.0f : 0.0f;
    float fx1ok = (ix1 >= 0 && ix1 < WW) ? 1.0f : 0.0f;
    float w00 = (1.0f-wy1)*(1.0f-wx1) * fy0ok * fx0ok;
    float w01 = (1.0f-wy1)*wx1        * fy0ok * fx1ok;
    float w10 = wy1*(1.0f-wx1)        * fy1ok * fx0ok;
    float w11 = wy1*wx1               * fy1ok * fx1ok;
    int cx0 = min(max(ix0,0),511), cx1 = min(max(ix1,0),511);
    int cy0 = min(max(iy0,0),511), cy1 = min(max(iy1,0),511);
    int i00 = cy0*WW + cx0, i01 = cy0*WW + cx1, i10 = cy1*WW + cx0, i11 = cy1*WW + cx1;
    size_t pix = (size_t)yy*WW + xx;
    #pragma unroll
    for (int c = 0; c < 3; ++c) {
        const float* pl = x + ((size_t)(b*3 + c)) * (HH*WW);
        float v = w00*pl[i00] + w01*pl[i01] + w10*pl[i10] + w11*pl[i11];
        timg [((size_t)(b*3 + c))*(HH*WW) + pix] = v;
        timgb[((size_t)(b*3 + c))*(HH*WW) + pix] = (bf16_t)v;
    }
    const float* sp = seg + (size_t)b * (HH*WW);
    float mv = w00*sp[i00] + w01*sp[i01] + w10*sp[i10] + w11*sp[i11];
    tmask[(size_t)b*(HH*WW) + pix] = mv;
}

// ---------------------------------------------------------------------------
// bf16 MFMA GEMM (verified r9/r12/r13): 64x64 tile, BK=64, 4 waves of 32x32,
// row&7 XOR swizzle, 2D XCD partition template param MC (NC = 8/MC).
// ---------------------------------------------------------------------------
enum { EPI_CONV=0, EPI_PE=1, EPI_QKV=2, EPI_PROJ=3, EPI_GELU=4, EPI_MLP2=5 };

template<int EPI>
__device__ __forceinline__ void gemm_epilogue64(
        f32x4 (&acc)[2][2], const float* bias, const float* extra,
        bf16_t* Cb, int bm, int bn, int wm, int wn,
        int rr, int g, int N) {
    #pragma unroll
    for (int i = 0; i < 2; ++i) {
        #pragma unroll
        for (int j = 0; j < 2; ++j) {
            #pragma unroll
            for (int r = 0; r < 4; ++r) {
                int m = bm + wm + i*16 + g*4 + r;
                int n = bn + wn + j*16 + rr;
                size_t o = (size_t)m * N + n;
                float v = acc[i][j][r] + bias[n];
                if (EPI == EPI_CONV) {
                    Cb[o] = (bf16_t)fmaxf(v, 0.0f);
                } else if (EPI == EPI_PE) {
                    Cb[o] = (bf16_t)(v + extra[(size_t)(m & 255)*N + n]);
                } else if (EPI == EPI_QKV) {
                    Cb[o] = (bf16_t)v;
                } else if (EPI == EPI_PROJ || EPI == EPI_MLP2) {
                    Cb[o] = (bf16_t)(v + (float)Cb[o]);
                } else if (EPI == EPI_GELU) {
                    float u = v;
                    float gl = 0.5f*u*(1.0f + tanh_fast(0.7978845608028654f*(u + 0.044715f*u*u*u)));
                    Cb[o] = (bf16_t)gl;
                }
            }
        }
    }
}

template<int EPI, int MC>
__global__ __launch_bounds__(256)
void gemm64_kernel(const bf16_t* __restrict__ A, const bf16_t* __restrict__ Bt,
                   const float* __restrict__ bias, const float* __restrict__ extra,
                   bf16_t* __restrict__ Cb,
                   int M, int N, int K) {
    constexpr int NC = 8 / MC;
    __shared__ __align__(16) bf16_t As[2][64*64];
    __shared__ __align__(16) bf16_t Bs[2][64*64];
    const int tid = threadIdx.x;
    const int nM = M >> 6, nN = N >> 6;
    const int SM = nM / MC, SN = nN / NC;
    const int xcd = blockIdx.x & 7;
    const int wdx = blockIdx.x >> 3;
    const int mc  = xcd / NC, nc = xcd % NC;
    const int bm = (mc*SM + wdx / SN) * 64;
    const int bn = (nc*SN + wdx % SN) * 64;
    const int lane = tid & 63, w = tid >> 6;
    const int rr = lane & 15, g = lane >> 4;
    const int wm = (w & 1) * 32, wn = (w >> 1) * 32;
    const int sr = tid >> 3;
    const int sc = ((tid & 7) ^ (sr & 7)) * 8;
    const bf16_t* gA0 = A  + (size_t)(bm + sr)      * K + sc;
    const bf16_t* gA1 = A  + (size_t)(bm + 32 + sr) * K + sc;
    const bf16_t* gB0 = Bt + (size_t)(bn + sr)      * K + sc;
    const bf16_t* gB1 = Bt + (size_t)(bn + 32 + sr) * K + sc;

    auto STAGE = [&](int buf, int k0) {
        gload16(gA0 + k0, As[buf] + w*512);
        gload16(gA1 + k0, As[buf] + 2048 + w*512);
        gload16(gB0 + k0, Bs[buf] + w*512);
        gload16(gB1 + k0, Bs[buf] + 2048 + w*512);
    };

    const int s0 = (0*4 + g) ^ (rr & 7);
    const int s1 = (1*4 + g) ^ (rr & 7);

    f32x4 acc[2][2] = {};
    STAGE(0, 0);
    __syncthreads();
    int cur = 0;
    for (int k0 = 0; k0 < K; k0 += 64) {
        if (k0 + 64 < K) STAGE(cur ^ 1, k0 + 64);
        bf16x8 af[2][2], bfv[2][2];
        #pragma unroll
        for (int i = 0; i < 2; ++i) {
            int ra = (wm + i*16 + rr) * 64;
            af[i][0] = *reinterpret_cast<const bf16x8*>(As[cur] + ra + s0*8);
            af[i][1] = *reinterpret_cast<const bf16x8*>(As[cur] + ra + s1*8);
            int rb = (wn + i*16 + rr) * 64;
            bfv[i][0] = *reinterpret_cast<const bf16x8*>(Bs[cur] + rb + s0*8);
            bfv[i][1] = *reinterpret_cast<const bf16x8*>(Bs[cur] + rb + s1*8);
        }
        #pragma unroll
        for (int ks = 0; ks < 2; ++ks)
            #pragma unroll
            for (int i = 0; i < 2; ++i)
                #pragma unroll
                for (int j = 0; j < 2; ++j)
                    acc[i][j] = __builtin_amdgcn_mfma_f32_16x16x32_bf16(
                        af[i][ks], bfv[j][ks], acc[i][j], 0, 0, 0);
        __syncthreads();
        cur ^= 1;
    }
    gemm_epilogue64<EPI>(acc, bias, extra, Cb, bm, bn, wm, wn, rr, g, N);
}

// conv GEMM: implicit im2col from bf16 image (verified r9/r12).
__global__ __launch_bounds__(256)
void gemm_conv64_kernel(const bf16_t* __restrict__ timgb, const bf16_t* __restrict__ Bt,
                        const float* __restrict__ bias, bf16_t* __restrict__ Cb) {
    const int N = NF_, K = KCONV;
    __shared__ __align__(16) bf16_t As[2][64*64];
    __shared__ __align__(16) bf16_t Bs[2][64*64];
    const int tid = threadIdx.x;
    const int nN   = N >> 6;
    const int nblk = (M_ >> 6) * nN;
    const int q    = nblk >> 3;
    const int id   = (blockIdx.x & 7) * q + (blockIdx.x >> 3);
    const int bm = (id / nN) * 64, bn = (id % nN) * 64;
    const int lane = tid & 63, w = tid >> 6;
    const int rr = lane & 15, g = lane >> 4;
    const int wm = (w & 1) * 32, wn = (w >> 1) * 32;
    const int sr = tid >> 3;
    const int s  = (tid & 7) ^ (sr & 7);
    int row0 = bm + sr, row1 = bm + 32 + sr;
    int b0 = row0 >> 8, py0 = (row0 >> 4) & 15, px0 = row0 & 15;
    int b1 = row1 >> 8, py1 = (row1 >> 4) & 15, px1 = row1 & 15;
    size_t off0 = (size_t)b0*786432 + py0*16384 + px0*32 + (s>>2)*512 + (s&3)*8;
    size_t off1 = (size_t)b1*786432 + py1*16384 + px1*32 + (s>>2)*512 + (s&3)*8;
    const bf16_t* gB0 = Bt + (size_t)(bn + sr)      * K + s*8;
    const bf16_t* gB1 = Bt + (size_t)(bn + 32 + sr) * K + s*8;

    auto STAGE = [&](int buf, int k0) {
        int c   = k0 >> 10;
        int ky0 = (k0 >> 5) & 31;
        size_t koff = (size_t)c*262144 + (size_t)ky0*512;
        gload16(timgb + off0 + koff, As[buf] + w*512);
        gload16(timgb + off1 + koff, As[buf] + 2048 + w*512);
        gload16(gB0 + k0, Bs[buf] + w*512);
        gload16(gB1 + k0, Bs[buf] + 2048 + w*512);
    };

    const int s0 = (0*4 + g) ^ (rr & 7);
    const int s1 = (1*4 + g) ^ (rr & 7);

    f32x4 acc[2][2] = {};
    STAGE(0, 0);
    __syncthreads();
    int cur = 0;
    for (int k0 = 0; k0 < K; k0 += 64) {
        if (k0 + 64 < K) STAGE(cur ^ 1, k0 + 64);
        bf16x8 af[2][2], bfv[2][2];
        #pragma unroll
        for (int i = 0; i < 2; ++i) {
            int ra = (wm + i*16 + rr) * 64;
            af[i][0] = *reinterpret_cast<const bf16x8*>(As[cur] + ra + s0*8);
            af[i][1] = *reinterpret_cast<const bf16x8*>(As[cur] + ra + s1*8);
            int rb = (wn + i*16 + rr) * 64;
            bfv[i][0] = *reinterpret_cast<const bf16x8*>(Bs[cur] + rb + s0*8);
            bfv[i][1] = *reinterpret_cast<const bf16x8*>(Bs[cur] + rb + s1*8);
        }
        #pragma unroll
        for (int ks = 0; ks < 2; ++ks)
            #pragma unroll
            for (int i = 0; i < 2; ++i)
                #pragma unroll
                for (int j = 0; j < 2; ++j)
                    acc[i][j] = __builtin_amdgcn_mfma_f32_16x16x32_bf16(
                        af[i][ks], bfv[j][ks], acc[i][j], 0, 0, 0);
        __syncthreads();
        cur ^= 1;
    }
    gemm_epilogue64<EPI_CONV>(acc, bias, nullptr, Cb, bm, bn, wm, wn, rr, g, N);
}

// ---------------------------------------------------------------------------
// layernorm rows of 768, bf16 in -> bf16 out (verified r12)
// ---------------------------------------------------------------------------
__global__ __launch_bounds__(256)
void ln_kernel(const bf16_t* __restrict__ x, const float* __restrict__ g,
               const float* __restrict__ be, bf16_t* __restrict__ out) {
    int r = blockIdx.x, tid = threadIdx.x;
    const bf16_t* xr = x + (size_t)r * EMB_;
    float v0 = (float)xr[tid], v1 = (float)xr[tid+256], v2 = (float)xr[tid+512];
    float s = v0+v1+v2, s2 = v0*v0 + v1*v1 + v2*v2;
    __shared__ float red[8];
    #pragma unroll
    for (int off = 32; off; off >>= 1) { s += __shfl_xor(s, off); s2 += __shfl_xor(s2, off); }
    if ((tid & 63) == 0) { red[tid>>6] = s; red[4 + (tid>>6)] = s2; }
    __syncthreads();
    s  = red[0]+red[1]+red[2]+red[3];
    s2 = red[4]+red[5]+red[6]+red[7];
    float mean = s * (1.0f/768.0f);
    float var  = s2 * (1.0f/768.0f) - mean*mean;
    float rstd = rsqrtf(var + 1e-5f);
    bf16_t* orow = out + (size_t)r * EMB_;
    orow[tid]     = (bf16_t)((v0-mean)*rstd*g[tid]     + be[tid]);
    orow[tid+256] = (bf16_t)((v1-mean)*rstd*g[tid+256] + be[tid+256]);
    orow[tid+512] = (bf16_t)((v2-mean)*rstd*g[tid+512] + be[tid+512]);
}

// ---------------------------------------------------------------------------
// attention: MFMA flash-chunked (verified r5-r13)
// ---------------------------------------------------------------------------
__global__ __launch_bounds__(256)
void attn_kernel5(const bf16_t* __restrict__ qkv, bf16_t* __restrict__ o) {
    __shared__ __align__(16) bf16_t Ks[256*72];
    __shared__ __align__(16) bf16_t Vt[64*264];
    __shared__ __align__(16) bf16_t Ps[4][64*72];
    const int tid  = threadIdx.x;
    const int lane = tid & 63, w = tid >> 6;
    const int rr   = lane & 15, g = lane >> 4;
    const int h = blockIdx.x % HEADS_;
    const int b = blockIdx.x / HEADS_;
    const bf16_t* base = qkv + (size_t)(b*256)*2304;

    {
        const bf16_t* kr = base + (size_t)tid*2304 + 768  + h*64;
        const bf16_t* vr = base + (size_t)tid*2304 + 1536 + h*64;
        bf16_t* kd = Ks + tid*72;
        #pragma unroll
        for (int c2 = 0; c2 < 8; ++c2) {
            *reinterpret_cast<bf16x8*>(kd + c2*8) =
                *reinterpret_cast<const bf16x8*>(kr + c2*8);
            bf16x8 v = *reinterpret_cast<const bf16x8*>(vr + c2*8);
            #pragma unroll
            for (int e = 0; e < 8; ++e)
                Vt[(c2*8 + e)*264 + tid] = v[e];
        }
    }

    bf16x8 qf[4][2];
    #pragma unroll
    for (int i = 0; i < 4; ++i)
        #pragma unroll
        for (int ks = 0; ks < 2; ++ks)
            qf[i][ks] = *reinterpret_cast<const bf16x8*>(
                base + (size_t)(w*64 + i*16 + rr)*2304 + h*64 + ks*32 + g*8);

    f32x4 oacc[4][4] = {};
    float lacc[4][4] = {};
    __syncthreads();

    bf16_t* Pw = Ps[w];
    for (int kc = 0; kc < 4; ++kc) {
        f32x4 sacc[4][4] = {};
        #pragma unroll
        for (int ks = 0; ks < 2; ++ks) {
            bf16x8 kf[4];
            #pragma unroll
            for (int j = 0; j < 4; ++j)
                kf[j] = *reinterpret_cast<const bf16x8*>(
                    Ks + (size_t)(kc*64 + j*16 + rr)*72 + ks*32 + g*8);
            #pragma unroll
            for (int i = 0; i < 4; ++i)
                #pragma unroll
                for (int j = 0; j < 4; ++j)
                    sacc[i][j] = __builtin_amdgcn_mfma_f32_16x16x32_bf16(
                        qf[i][ks], kf[j], sacc[i][j], 0, 0, 0);
        }
        #pragma unroll
        for (int i = 0; i < 4; ++i) {
            #pragma unroll
            for (int r = 0; r < 4; ++r) {
                int prow = i*16 + g*4 + r;
                float ps = 0.0f;
                #pragma unroll
                for (int j = 0; j < 4; ++j) {
                    float p = __expf(sacc[i][j][r] * 0.125f);
                    ps += p;
                    Pw[prow*72 + j*16 + rr] = (bf16_t)p;
                }
                lacc[i][r] += ps;
            }
        }
        #pragma unroll
        for (int ks = 0; ks < 2; ++ks) {
            bf16x8 pa[4], vb[4];
            #pragma unroll
            for (int i = 0; i < 4; ++i)
                pa[i] = *reinterpret_cast<const bf16x8*>(
                    Pw + (size_t)(i*16 + rr)*72 + ks*32 + g*8);
            #pragma unroll
            for (int n = 0; n < 4; ++n)
                vb[n] = *reinterpret_cast<const bf16x8*>(
                    Vt + (size_t)(n*16 + rr)*264 + kc*64 + ks*32 + g*8);
            #pragma unroll
            for (int i = 0; i < 4; ++i)
                #pragma unroll
                for (int n = 0; n < 4; ++n)
                    oacc[i][n] = __builtin_amdgcn_mfma_f32_16x16x32_bf16(
                        pa[i], vb[n], oacc[i][n], 0, 0, 0);
        }
    }

    #pragma unroll
    for (int i = 0; i < 4; ++i) {
        #pragma unroll
        for (int r = 0; r < 4; ++r) {
            float v = lacc[i][r];
            v += __shfl_xor(v, 1);
            v += __shfl_xor(v, 2);
            v += __shfl_xor(v, 4);
            v += __shfl_xor(v, 8);
            lacc[i][r] = 1.0f / v;
        }
    }
    #pragma unroll
    for (int i = 0; i < 4; ++i) {
        #pragma unroll
        for (int r = 0; r < 4; ++r) {
            int qrow = w*64 + i*16 + g*4 + r;
            bf16_t* orow = o + (size_t)(b*256 + qrow)*EMB_ + h*64;
            float inv = lacc[i][r];
            #pragma unroll
            for (int n = 0; n < 4; ++n)
                orow[n*16 + rr] = (bf16_t)(oacc[i][n][r] * inv);
        }
    }
}

// ---------------------------------------------------------------------------
// head (verified r12): fused feats+fc+softmax, 96 blocks x 768 threads
// ---------------------------------------------------------------------------
__global__ __launch_bounds__(768)
void head_kernel2(const bf16_t* __restrict__ tok, const float* __restrict__ fcw,
                  const float* __restrict__ fcb, float* __restrict__ scores) {
    const int bx[6][4] = {{0,6,0,8},{4,11,0,8},{9,16,0,8},{0,6,8,16},{4,11,8,16},{9,16,8,16}};
    int box = blockIdx.x % 6, b = blockIdx.x / 6;
    int r0 = bx[box][0], r1 = bx[box][1], c0 = bx[box][2], c1 = bx[box][3];
    int rh = r1 - r0, rw = c1 - c0;
    __shared__ float wl[256];
    __shared__ float red[48];
    int tid = threadIdx.x;
    if (tid < 256) {
        int py = tid >> 4, px = tid & 15;
        float w = 0.0f;
        if (py >= r0 && py < r1 && px >= c0 && px < c1) {
            int ly = py - r0, lx = px - c0;
            float cy = 0.0f, cx = 0.0f;
            for (int o = 0; o < 16; ++o) {
                float sy = (o + 0.5f) * (float)rh * (1.0f/16.0f) - 0.5f;
                sy = fminf(fmaxf(sy, 0.0f), (float)(rh - 1));
                int i0 = (int)floorf(sy); float t = sy - (float)i0;
                if (ly == i0)     cy += 1.0f - t;
                if (ly == i0 + 1) cy += t;
                float sx = (o + 0.5f) * (float)rw * (1.0f/16.0f) - 0.5f;
                sx = fminf(fmaxf(sx, 0.0f), (float)(rw - 1));
                int j0 = (int)floorf(sx); float u = sx - (float)j0;
                if (lx == j0)     cx += 1.0f - u;
                if (lx == j0 + 1) cx += u;
            }
            w = (cy * (1.0f/16.0f)) * (cx * (1.0f/16.0f));
        }
        wl[tid] = w;
    }
    __syncthreads();
    float f = 0.0f;
    for (int iy = r0; iy < r1; ++iy)
        for (int ix = c0; ix < c1; ++ix) {
            int p = iy*16 + ix;
            f = fmaf(wl[p], (float)tok[((size_t)(b*256 + p))*EMB_ + tid], f);
        }
    float p0 = f * fcw[tid*4+0];
    float p1 = f * fcw[tid*4+1];
    float p2 = f * fcw[tid*4+2];
    float p3 = f * fcw[tid*4+3];
    #pragma unroll
    for (int off = 32; off; off >>= 1) {
        p0 += __shfl_xor(p0, off); p1 += __shfl_xor(p1, off);
        p2 += __shfl_xor(p2, off); p3 += __shfl_xor(p3, off);
    }
    int wv = tid >> 6;
    if ((tid & 63) == 0) {
        red[wv*4+0] = p0; red[wv*4+1] = p1; red[wv*4+2] = p2; red[wv*4+3] = p3;
    }
    __syncthreads();
    if (tid == 0) {
        float lg[4];
        #pragma unroll
        for (int cc = 0; cc < 4; ++cc) {
            float s = fcb[cc];
            for (int v = 0; v < 12; ++v) s += red[v*4+cc];
            lg[cc] = s;
        }
        float mx = fmaxf(fmaxf(lg[0],lg[1]), fmaxf(lg[2],lg[3]));
        float e0 = expf(lg[0]-mx), e1 = expf(lg[1]-mx), e2 = expf(lg[2]-mx), e3 = expf(lg[3]-mx);
        float inv = 1.0f/(e0+e1+e2+e3);
        float* out = scores + (size_t)(b*6 + box)*4;
        out[0] = e0*inv; out[1] = e1*inv; out[2] = e2*inv; out[3] = e3*inv;
    }
}

// ===========================================================================
extern "C" void kernel_launch(void* const* d_in, const int* in_sizes, int n_in,
                              void* d_out, int out_size, void* d_ws, size_t ws_size,
                              hipStream_t stream) {
    (void)in_sizes; (void)n_in; (void)out_size; (void)ws_size;
    const float* x       = (const float*)d_in[0];
    const float* lm      = (const float*)d_in[1];
    const float* stn_w1  = (const float*)d_in[2];
    const float* stn_b1  = (const float*)d_in[3];
    const float* stn_w2  = (const float*)d_in[4];
    const float* stn_b2  = (const float*)d_in[5];
    const float* conv_w  = (const float*)d_in[6];
    const float* conv_b  = (const float*)d_in[7];
    const float* pe_w    = (const float*)d_in[8];
    const float* pe_b    = (const float*)d_in[9];
    const float* pos     = (const float*)d_in[10];
    const float* ln1_g   = (const float*)d_in[11];
    const float* ln1_b   = (const float*)d_in[12];
    const float* qkv_w   = (const float*)d_in[13];
    const float* qkv_b   = (const float*)d_in[14];
    const float* proj_w  = (const float*)d_in[15];
    const float* proj_b  = (const float*)d_in[16];
    const float* ln2_g   = (const float*)d_in[17];
    const float* ln2_b   = (const float*)d_in[18];
    const float* mlp_w1  = (const float*)d_in[19];
    const float* mlp_b1  = (const float*)d_in[20];
    const float* mlp_w2  = (const float*)d_in[21];
    const float* mlp_b2  = (const float*)d_in[22];
    const float* fc_w    = (const float*)d_in[23];
    const float* fc_b    = (const float*)d_in[24];

    float* out    = (float*)d_out;
    float* scores = out;
    float* timg   = out + 384;
    float* tmask  = out + 384 + (size_t)B_*3*HH*WW;

    char* ws = (char*)d_ws;
    size_t off = 0;
    auto alloc = [&](size_t bytes) {
        off = (off + 255) & ~(size_t)255;
        void* p = ws + off; off += bytes; return p;
    };
    char*   slotBig = (char*)alloc(25165824);            // seg -> hidden
    char*   slotT   = (char*)alloc((size_t)B_*3*HH*WW*2); // timgb -> qkvb
    char*   slotC   = (char*)alloc((size_t)M_*NF_*2);     // featC -> obuf
    bf16_t* tok     = (bf16_t*)alloc((size_t)M_*EMB_*2);
    bf16_t* tbuf    = (bf16_t*)alloc((size_t)M_*EMB_*2);
    bf16_t* conv_wb = (bf16_t*)alloc((size_t)NF_*KCONV*2);
    bf16_t* pe_wb   = (bf16_t*)alloc((size_t)EMB_*NF_*2);
    bf16_t* qkv_wb  = (bf16_t*)alloc((size_t)3*EMB_*EMB_*2);
    bf16_t* proj_wb = (bf16_t*)alloc((size_t)EMB_*EMB_*2);
    bf16_t* mlp1_wb = (bf16_t*)alloc((size_t)4*EMB_*EMB_*2);
    bf16_t* mlp2_wb = (bf16_t*)alloc((size_t)EMB_*4*EMB_*2);
    float*  w1t     = (float*)alloc(50*1024*4);
    float*  theta   = (float*)alloc(96*4);

    float*  seg    = (float*)slotBig;
    bf16_t* hidden = (bf16_t*)slotBig;
    bf16_t* timgb  = (bf16_t*)slotT;
    bf16_t* qkvb   = (bf16_t*)slotT;
    bf16_t* featC  = (bf16_t*)slotC;
    bf16_t* obuf   = (bf16_t*)slotC;

    // weight prep (fused)
    prep_weights_kernel<<<9416, 256, 0, stream>>>(
        conv_w, conv_wb, stn_w1, w1t, pe_w, pe_wb, qkv_w, qkv_wb,
        proj_w, proj_wb, mlp_w1, mlp1_wb, mlp_w2, mlp2_wb);

    // mask path
    hipMemsetAsync(seg, 0, (size_t)B_*HH*WW*sizeof(float), stream);
    raster_kernel<<<B_, 128, 0, stream>>>(lm, seg);
    stn3_kernel<<<B_, 1024, 0, stream>>>(seg, w1t, stn_b1, stn_w2, stn_b2, theta);
    gridsample_kernel<<<(B_*HH*WW)/256, 256, 0, stream>>>(x, seg, theta, timg, tmask, timgb);

    // conv as implicit-im2col GEMM (1024 blocks)
    gemm_conv64_kernel<<<(M_/64)*(NF_/64), 256, 0, stream>>>(
        timgb, conv_wb, conv_b, featC);

    // patch embed + pos -> tok (bf16 residual)   [768 blocks, MC=8]
    gemm64_kernel<EPI_PE, 8><<<(M_/64)*(EMB_/64), 256, 0, stream>>>(
        featC, pe_wb, pe_b, pos, tok, M_, EMB_, NF_);

    // LN1 -> qkv   [2304 blocks, MC=4: per-XCD 3.3MB fits L2]
    ln_kernel<<<M_, 256, 0, stream>>>(tok, ln1_g, ln1_b, tbuf);
    gemm64_kernel<EPI_QKV, 4><<<(M_/64)*(3*EMB_/64), 256, 0, stream>>>(
        tbuf, qkv_wb, qkv_b, nullptr, qkvb, M_, 3*EMB_, EMB_);

    // attention (MFMA)
    attn_kernel5<<<B_*HEADS_, 256, 0, stream>>>(qkvb, obuf);

    // proj + residual   [768 blocks, MC=8]
    gemm64_kernel<EPI_PROJ, 8><<<(M_/64)*(EMB_/64), 256, 0, stream>>>(
        obuf, proj_wb, proj_b, nullptr, tok, M_, EMB_, EMB_);

    // LN2 -> mlp   [mlp1 3072 blocks MC=4 (3.9MB/XCD fits L2); mlp2 MC=8]
    ln_kernel<<<M_, 256, 0, stream>>>(tok, ln2_g, ln2_b, tbuf);
    gemm64_kernel<EPI_GELU, 4><<<(M_/64)*(4*EMB_/64), 256, 0, stream>>>(
        tbuf, mlp1_wb, mlp_b1, nullptr, hidden, M_, 4*EMB_, EMB_);
    gemm64_kernel<EPI_MLP2, 8><<<(M_/64)*(EMB_/64), 256, 0, stream>>>(
        hidden, mlp2_wb, mlp_b2, nullptr, tok, M_, EMB_, 4*EMB_);

    // head
    head_kernel2<<<B_*6, 768, 0, stream>>>(tok, fc_w, fc_b, scores);
}